// Round 1
// baseline (535.235 us; speedup 1.0000x reference)
//
#include <hip/hip_runtime.h>
#include <math.h>

#define BATCH 16
#define CIN 4
#define LEN 300000
#define KW 11
#define LC (LEN - KW + 1)   // 299990
#define LEAK 1e-4f
#define EPS_N 1e-12f

// ws layout (stats zeroed by hipMemsetAsync each call):
//   [0..128)    double absum[16]
//   [128..256)  double esum[16]
//   [256..384)  double s1[16]
//   [384..512)  double s2[16]
//   [512..576)  unsigned maxenc[16]
//   [1024.. )   float ch[BATCH*LC]

__device__ inline unsigned enc_f32(float x) {
    unsigned u = __float_as_uint(x);
    return (u & 0x80000000u) ? ~u : (u | 0x80000000u);
}
__device__ inline float dec_f32(unsigned e) {
    unsigned u = (e & 0x80000000u) ? (e & 0x7FFFFFFFu) : ~e;
    return __uint_as_float(u);
}

__global__ __launch_bounds__(256) void conv_stats(
    const float* __restrict__ data, const float* __restrict__ W,
    const float* __restrict__ bias, const int* __restrict__ aidx,
    double* __restrict__ absum, unsigned* __restrict__ maxenc,
    float* __restrict__ ch)
{
    const int b   = blockIdx.y;
    const int l0  = blockIdx.x * 256;
    const int tid = threadIdx.x;

    __shared__ float sw[CIN * KW];
    __shared__ float sbias;
    __shared__ float sd[CIN][272];   // 256 + 10 halo, padded

    const int a = aidx[0];
    if (tid < CIN * KW) sw[tid] = W[a * CIN * KW + tid];
    if (tid == 0) sbias = bias[a];

    const float* dbase = data + (size_t)b * (CIN * (size_t)LEN);
    for (int idx = tid; idx < CIN * 266; idx += 256) {
        int c   = idx / 266;
        int off = idx - c * 266;
        int l   = l0 + off;
        sd[c][off] = (l < LEN) ? dbase[(size_t)c * LEN + l] : 0.0f;
    }
    __syncthreads();

    const int l = l0 + tid;
    float aabs = 0.0f;
    float amax = -INFINITY;
    if (l < LC) {
        float acc = sbias;
#pragma unroll
        for (int c = 0; c < CIN; ++c) {
#pragma unroll
            for (int k = 0; k < KW; ++k)
                acc = fmaf(sd[c][tid + k], sw[c * KW + k], acc);
        }
        float y = acc > 0.0f ? acc : LEAK * acc;
        ch[(size_t)b * LC + l] = y;
        aabs = fabsf(y);
        amax = y;
    }

    // block reduction: 4 waves of 64
#pragma unroll
    for (int off = 32; off > 0; off >>= 1) {
        aabs += __shfl_down(aabs, off);
        amax  = fmaxf(amax, __shfl_down(amax, off));
    }
    __shared__ float wabs[4];
    __shared__ float wmax[4];
    const int wave = tid >> 6;
    if ((tid & 63) == 0) { wabs[wave] = aabs; wmax[wave] = amax; }
    __syncthreads();
    if (tid == 0) {
        float ta = (wabs[0] + wabs[1]) + (wabs[2] + wabs[3]);
        float tm = fmaxf(fmaxf(wmax[0], wmax[1]), fmaxf(wmax[2], wmax[3]));
        atomicAdd(&absum[b], (double)ta);
        atomicMax(&maxenc[b], enc_f32(tm));
    }
}

__global__ __launch_bounds__(256) void softmax_pass(
    const float* __restrict__ ch, const double* __restrict__ absum,
    const unsigned* __restrict__ maxenc, float* __restrict__ chan_out,
    double* __restrict__ esum, double* __restrict__ s1, double* __restrict__ s2)
{
    const int b   = blockIdx.y;
    const int tid = threadIdx.x;
    const int l   = blockIdx.x * 256 + tid;

    double te = 0.0, t1 = 0.0, t2 = 0.0;
    if (l < LC) {
        float denom = fmaxf((float)absum[b], EPS_N);
        float mx    = dec_f32(maxenc[b]) / denom;
        float v     = ch[(size_t)b * LC + l];
        float c     = v / denom;
        chan_out[(size_t)b * LC + l] = c;
        float t = expf(c - mx);
        double x = (double)l;
        te = (double)t;
        t1 = (double)t * x;
        t2 = (double)t * x * x;
    }

#pragma unroll
    for (int off = 32; off > 0; off >>= 1) {
        te += __shfl_down(te, off);
        t1 += __shfl_down(t1, off);
        t2 += __shfl_down(t2, off);
    }
    __shared__ double we[4], w1[4], w2[4];
    const int wave = tid >> 6;
    if ((tid & 63) == 0) { we[wave] = te; w1[wave] = t1; w2[wave] = t2; }
    __syncthreads();
    if (tid == 0) {
        atomicAdd(&esum[b], (we[0] + we[1]) + (we[2] + we[3]));
        atomicAdd(&s1[b],   (w1[0] + w1[1]) + (w1[2] + w1[3]));
        atomicAdd(&s2[b],   (w2[0] + w2[1]) + (w2[2] + w2[3]));
    }
}

__global__ void finalize(const double* __restrict__ esum,
                         const double* __restrict__ s1,
                         const double* __restrict__ s2,
                         float* __restrict__ out)
{
    const int b = threadIdx.x;
    if (b < BATCH) {
        double E    = esum[b];
        double mean = s1[b] / E;
        double var  = s2[b] / E - mean * mean;

        const double n   = (double)LC;
        const double nm1 = n - 1.0;
        // power sums over l = 0..n-1
        double S1p = 0.5 * n * nm1;
        double S2p = nm1 * n * (2.0 * n - 1.0) / 6.0;
        double S3p = S1p * S1p;
        double S4p = S2p * (3.0 * n * n - 3.0 * n - 1.0) / 5.0;

        double mu  = mean;
        double mu2 = mu * mu;
        double P3 = S3p - 3.0 * mu * S2p + 3.0 * mu2 * S1p - n * mu * mu2;
        double P4 = S4p - 4.0 * mu * S3p + 6.0 * mu2 * S2p
                    - 4.0 * mu * mu2 * S1p + n * mu2 * mu2;

        double sv   = sqrt(var);
        double skew = P3 / (n * sv * sv * sv);
        double kurt = P4 / (n * var * var) - 3.0;

        out[b]         = (float)skew;
        out[BATCH + b] = (float)kurt;
    }
}

extern "C" void kernel_launch(void* const* d_in, const int* in_sizes, int n_in,
                              void* d_out, int out_size, void* d_ws, size_t ws_size,
                              hipStream_t stream) {
    const float* data = (const float*)d_in[0];
    const float* W    = (const float*)d_in[1];
    const float* bias = (const float*)d_in[2];
    const int*   aidx = (const int*)d_in[3];
    float* out = (float*)d_out;

    char* ws = (char*)d_ws;
    double*   absum  = (double*)(ws + 0);
    double*   esum   = (double*)(ws + 128);
    double*   s1     = (double*)(ws + 256);
    double*   s2     = (double*)(ws + 384);
    unsigned* maxenc = (unsigned*)(ws + 512);
    float*    ch     = (float*)(ws + 1024);

    hipMemsetAsync(d_ws, 0, 1024, stream);

    dim3 grid((LC + 255) / 256, BATCH);
    conv_stats<<<grid, dim3(256), 0, stream>>>(data, W, bias, aidx, absum, maxenc, ch);
    // channel output lives after skews[16] + kts[16]
    softmax_pass<<<grid, dim3(256), 0, stream>>>(ch, absum, maxenc, out + 2 * BATCH,
                                                 esum, s1, s2);
    finalize<<<1, 64, 0, stream>>>(esum, s1, s2, out);
}

// Round 2
// 148.521 us; speedup vs baseline: 3.6038x; 3.6038x over previous
//
#include <hip/hip_runtime.h>
#include <math.h>

#define BATCH 16
#define CIN 4
#define LEN 300000
#define KW 11
#define LC (LEN - KW + 1)   // 299990
#define LCP 300000          // padded row stride for ch workspace (mult of 4)
#define LEAK 1e-4f
#define EPS_N 1e-12f

#define NB 64               // blocks per batch (<=64 so one wave reduces)
#define CHUNK 4688          // ceil(LC/NB), multiple of 4
#define TILE 1024
#define ROW 1040            // TILE + 16 floats per LDS row

// ws layout (no memset needed; every slot written before read):
//   absP   double[BATCH*NB]        @ 0       (8192 B)
//   maxP   float [BATCH*NB]        @ 8192    (4096 B)
//   stats  float [BATCH*2]         @ 12288   (128 B)   {denom, max}
//   sP     double[BATCH*NB*3]      @ 12416   (24576 B)
//   ch     float [BATCH*LCP]       @ 65536   (19.2 MB)

__global__ __launch_bounds__(256) void conv_stats(
    const float* __restrict__ data, const float* __restrict__ W,
    const float* __restrict__ bias, const int* __restrict__ aidx,
    double* __restrict__ absP, float* __restrict__ maxP,
    float* __restrict__ ch)
{
    const int b = blockIdx.y, j = blockIdx.x, tid = threadIdx.x;
    __shared__ float sd[CIN][ROW];

    const int a = aidx[0];
    float w[CIN * KW];
#pragma unroll
    for (int k = 0; k < CIN * KW; ++k) w[k] = W[a * CIN * KW + k];
    const float sb = bias[a];

    const float* dbase = data + (size_t)b * (CIN * (size_t)LEN);
    float* chrow = ch + (size_t)b * LCP;

    const int cstart = j * CHUNK;
    const int cend   = min(cstart + CHUNK, LC);

    float aabs = 0.0f;
    float amax = -INFINITY;

    for (int l0 = cstart; l0 < cend; l0 += TILE) {
        const int n    = min(TILE, cend - l0);
        const int need = n + 14;            // n+10 halo, +4 for float4 over-read
        const int nv   = (need + 3) >> 2;   // float4s per channel
        __syncthreads();                    // protect LDS reuse
#pragma unroll
        for (int c = 0; c < CIN; ++c) {
            const float* src = dbase + (size_t)c * LEN + l0;
            for (int i = tid; i < nv; i += 256) {
                const int off = i << 2;
                float4 v;
                if (l0 + off + 3 < LEN) {
                    v = *(const float4*)(src + off);
                } else {
                    v.x = (l0 + off     < LEN) ? src[off]     : 0.0f;
                    v.y = (l0 + off + 1 < LEN) ? src[off + 1] : 0.0f;
                    v.z = (l0 + off + 2 < LEN) ? src[off + 2] : 0.0f;
                    v.w = (l0 + off + 3 < LEN) ? src[off + 3] : 0.0f;
                }
                *(float4*)(&sd[c][off]) = v;
            }
        }
        __syncthreads();

        const int n4 = n >> 2;
        for (int q = tid; q < n4; q += 256) {
            const int o = q << 2;
            float acc0 = sb, acc1 = sb, acc2 = sb, acc3 = sb;
#pragma unroll
            for (int c = 0; c < CIN; ++c) {
                float x[16];
                const float4 v0 = *(const float4*)(&sd[c][o]);
                const float4 v1 = *(const float4*)(&sd[c][o + 4]);
                const float4 v2 = *(const float4*)(&sd[c][o + 8]);
                const float4 v3 = *(const float4*)(&sd[c][o + 12]);
                x[0] = v0.x;  x[1] = v0.y;  x[2]  = v0.z;  x[3]  = v0.w;
                x[4] = v1.x;  x[5] = v1.y;  x[6]  = v1.z;  x[7]  = v1.w;
                x[8] = v2.x;  x[9] = v2.y;  x[10] = v2.z;  x[11] = v2.w;
                x[12] = v3.x; x[13] = v3.y; x[14] = v3.z;  x[15] = v3.w;
#pragma unroll
                for (int k = 0; k < KW; ++k) {
                    const float wv = w[c * KW + k];
                    acc0 = fmaf(x[k],     wv, acc0);
                    acc1 = fmaf(x[k + 1], wv, acc1);
                    acc2 = fmaf(x[k + 2], wv, acc2);
                    acc3 = fmaf(x[k + 3], wv, acc3);
                }
            }
            float4 y;
            y.x = acc0 > 0.0f ? acc0 : LEAK * acc0;
            y.y = acc1 > 0.0f ? acc1 : LEAK * acc1;
            y.z = acc2 > 0.0f ? acc2 : LEAK * acc2;
            y.w = acc3 > 0.0f ? acc3 : LEAK * acc3;
            *(float4*)(chrow + l0 + o) = y;
            aabs += (fabsf(y.x) + fabsf(y.y)) + (fabsf(y.z) + fabsf(y.w));
            amax = fmaxf(amax, fmaxf(fmaxf(y.x, y.y), fmaxf(y.z, y.w)));
        }
        // tail (last tile only, n not multiple of 4 or n4*4 < n)
        for (int q = (n4 << 2) + tid; q < n; q += 256) {
            float acc = sb;
#pragma unroll
            for (int c = 0; c < CIN; ++c)
#pragma unroll
                for (int k = 0; k < KW; ++k)
                    acc = fmaf(sd[c][q + k], w[c * KW + k], acc);
            float y = acc > 0.0f ? acc : LEAK * acc;
            chrow[l0 + q] = y;
            aabs += fabsf(y);
            amax = fmaxf(amax, y);
        }
    }

    // block reduction: no atomics, write per-block partial
#pragma unroll
    for (int off = 32; off; off >>= 1) {
        aabs += __shfl_down(aabs, off);
        amax  = fmaxf(amax, __shfl_down(amax, off));
    }
    __shared__ float ra[4], rm[4];
    const int wv = tid >> 6;
    if ((tid & 63) == 0) { ra[wv] = aabs; rm[wv] = amax; }
    __syncthreads();
    if (tid == 0) {
        absP[b * NB + j] = (double)((ra[0] + ra[1]) + (ra[2] + ra[3]));
        maxP[b * NB + j] = fmaxf(fmaxf(rm[0], rm[1]), fmaxf(rm[2], rm[3]));
    }
}

__global__ void reduce1(const double* __restrict__ absP,
                        const float* __restrict__ maxP,
                        float* __restrict__ stats)
{
    const int b = blockIdx.x, t = threadIdx.x;
    double s = (t < NB) ? absP[b * NB + t] : 0.0;
    float  m = (t < NB) ? maxP[b * NB + t] : -INFINITY;
#pragma unroll
    for (int off = 32; off; off >>= 1) {
        s += __shfl_down(s, off);
        m  = fmaxf(m, __shfl_down(m, off));
    }
    if (t == 0) {
        stats[b * 2]     = fmaxf((float)s, EPS_N);  // denom
        stats[b * 2 + 1] = m;                        // max
    }
}

__global__ __launch_bounds__(256) void softmax_pass(
    const float* __restrict__ ch, const float* __restrict__ stats,
    float* __restrict__ chan_out, double* __restrict__ sP)
{
    const int b = blockIdx.y, j = blockIdx.x, tid = threadIdx.x;
    const float denom = stats[b * 2];
    const float inv   = 1.0f / denom;
    const float mx    = stats[b * 2 + 1] * inv;

    const float* src = ch + (size_t)b * LCP;
    float* dst = chan_out + (size_t)b * LC;   // row base only 8B-aligned for odd b

    const int cstart = j * CHUNK;
    const int cend   = min(cstart + CHUNK, LC);

    double te = 0.0, t1 = 0.0, t2 = 0.0;

    const int nfull = (cend - cstart) >> 2;
    for (int q = tid; q < nfull; q += 256) {
        const int l = cstart + (q << 2);
        const float4 v = *(const float4*)(src + l);
        float cc[4] = { v.x * inv, v.y * inv, v.z * inv, v.w * inv };
        float2 p0 = { cc[0], cc[1] };
        float2 p1 = { cc[2], cc[3] };
        *(float2*)(dst + l)     = p0;   // float2: 8B alignment holds for all b
        *(float2*)(dst + l + 2) = p1;
#pragma unroll
        for (int u = 0; u < 4; ++u) {
            const float e = expf(cc[u] - mx);
            const double xd = (double)(l + u);
            te += (double)e;
            t1 += (double)e * xd;
            t2 += (double)e * xd * xd;
        }
    }
    for (int l = cstart + (nfull << 2) + tid; l < cend; l += 256) {
        const float c = src[l] * inv;
        dst[l] = c;
        const float e = expf(c - mx);
        const double xd = (double)l;
        te += (double)e;
        t1 += (double)e * xd;
        t2 += (double)e * xd * xd;
    }

#pragma unroll
    for (int off = 32; off; off >>= 1) {
        te += __shfl_down(te, off);
        t1 += __shfl_down(t1, off);
        t2 += __shfl_down(t2, off);
    }
    __shared__ double we[4], w1[4], w2[4];
    const int wv = tid >> 6;
    if ((tid & 63) == 0) { we[wv] = te; w1[wv] = t1; w2[wv] = t2; }
    __syncthreads();
    if (tid == 0) {
        double* p = sP + (size_t)(b * NB + j) * 3;
        p[0] = (we[0] + we[1]) + (we[2] + we[3]);
        p[1] = (w1[0] + w1[1]) + (w1[2] + w1[3]);
        p[2] = (w2[0] + w2[1]) + (w2[2] + w2[3]);
    }
}

__global__ void finalize(const double* __restrict__ sP, float* __restrict__ out)
{
    const int b = blockIdx.x, t = threadIdx.x;
    double te = 0.0, t1 = 0.0, t2 = 0.0;
    if (t < NB) {
        const double* p = sP + (size_t)(b * NB + t) * 3;
        te = p[0]; t1 = p[1]; t2 = p[2];
    }
#pragma unroll
    for (int off = 32; off; off >>= 1) {
        te += __shfl_down(te, off);
        t1 += __shfl_down(t1, off);
        t2 += __shfl_down(t2, off);
    }
    if (t == 0) {
        const double E    = te;
        const double mean = t1 / E;
        const double var  = t2 / E - mean * mean;

        const double n   = (double)LC;
        const double nm1 = n - 1.0;
        const double S1p = 0.5 * n * nm1;
        const double S2p = nm1 * n * (2.0 * n - 1.0) / 6.0;
        const double S3p = S1p * S1p;
        const double S4p = S2p * (3.0 * n * n - 3.0 * n - 1.0) / 5.0;

        const double mu  = mean;
        const double mu2 = mu * mu;
        const double P3 = S3p - 3.0 * mu * S2p + 3.0 * mu2 * S1p - n * mu * mu2;
        const double P4 = S4p - 4.0 * mu * S3p + 6.0 * mu2 * S2p
                          - 4.0 * mu * mu2 * S1p + n * mu2 * mu2;

        const double sv   = sqrt(var);
        const double skew = P3 / (n * sv * sv * sv);
        const double kurt = P4 / (n * var * var) - 3.0;

        out[b]         = (float)skew;
        out[BATCH + b] = (float)kurt;
    }
}

extern "C" void kernel_launch(void* const* d_in, const int* in_sizes, int n_in,
                              void* d_out, int out_size, void* d_ws, size_t ws_size,
                              hipStream_t stream) {
    const float* data = (const float*)d_in[0];
    const float* W    = (const float*)d_in[1];
    const float* bias = (const float*)d_in[2];
    const int*   aidx = (const int*)d_in[3];
    float* out = (float*)d_out;

    char* ws = (char*)d_ws;
    double* absP  = (double*)(ws + 0);
    float*  maxP  = (float*) (ws + 8192);
    float*  stats = (float*) (ws + 12288);
    double* sP    = (double*)(ws + 12416);
    float*  ch    = (float*) (ws + 65536);

    dim3 grid(NB, BATCH);
    conv_stats<<<grid, dim3(256), 0, stream>>>(data, W, bias, aidx, absP, maxP, ch);
    reduce1<<<dim3(BATCH), dim3(64), 0, stream>>>(absP, maxP, stats);
    softmax_pass<<<grid, dim3(256), 0, stream>>>(ch, stats, out + 2 * BATCH, sP);
    finalize<<<dim3(BATCH), dim3(64), 0, stream>>>(sP, out);
}